// Round 1
// baseline (297.266 us; speedup 1.0000x reference)
//
#include <hip/hip_runtime.h>
#include <hip/hip_bf16.h>
#include <stdint.h>

// FPNAttentionV2: 7x conv1x1 + 1x conv3x3s2, all as bf16-MFMA GEMMs with NHWC outputs.
// x1: [2,256,128,128] f32, x2: [2,256,64,64] f32. All outputs NHWC f32.

typedef __attribute__((ext_vector_type(8))) __bf16 bf16x8;
typedef __attribute__((ext_vector_type(4))) float f32x4;

typedef const __attribute__((address_space(1))) uint32_t* gptr_t;
typedef __attribute__((address_space(3))) uint32_t* lptr_t;

__device__ __forceinline__ void cp16(void* lds, const void* g) {
  // async global->LDS, 16B/lane; LDS dest is wave-uniform base + lane*16
  gptr_t gp = reinterpret_cast<gptr_t>(reinterpret_cast<uintptr_t>(g));
  lptr_t lp = reinterpret_cast<lptr_t>(
      static_cast<uint32_t>(reinterpret_cast<uintptr_t>(lds)));
  __builtin_amdgcn_global_load_lds(gp, lp, 16, 0, 0);
}

// ---------------- NCHW f32 -> NHWC bf16 (optionally +1 zero pad ring) ----------------
// grid: x = w-tile (W/64), y = c-tile (256/64), z = b*H + h ; block 256
__global__ void nchw2nhwc_bf16(const float* __restrict__ src,
                               uint16_t* __restrict__ dst,
                               int H, int W, int pad) {
  __shared__ float tile[64][65];
  const int tid = threadIdx.x;
  const int tx = tid & 63;
  const int tg = tid >> 6;
  const int b = blockIdx.z / H;
  const int h = blockIdx.z - b * H;
  const int wt = blockIdx.x * 64;
  const int ct = blockIdx.y * 64;
  const float* s = src + ((long)(b * 256 + ct) * H + h) * W + wt;
  const long cstride = (long)H * W;
#pragma unroll
  for (int i = 0; i < 16; i++) {
    const int cl = tg * 16 + i;
    tile[cl][tx] = s[(long)cl * cstride + tx];
  }
  __syncthreads();
  const int Wp = W + 2 * pad;
  __hip_bfloat16* d = reinterpret_cast<__hip_bfloat16*>(dst);
  const long dbase =
      (((long)(b * (H + 2 * pad) + h + pad)) * Wp + pad + wt) * 256 + ct + tx;
#pragma unroll
  for (int j = 0; j < 16; j++) {
    const int wl = tg * 16 + j;
    d[dbase + (long)wl * 256] = __float2bfloat16(tile[tx][wl]);
  }
}

// ---------------- weights f32 -> bf16 ----------------
struct WArgs {
  const float* w1[7];  // q1,q2,ks1,ks2,kup,v1,v2  each [256,256] row-major [O][C]
  const float* kdw;    // [256,256,3,3]
};

__global__ void convert_weights(WArgs a, uint16_t* __restrict__ wb,
                                uint16_t* __restrict__ wt) {
  const int idx = blockIdx.x * 256 + threadIdx.x;
  if (idx < 7 * 65536) {
    const int which = idx >> 16;
    reinterpret_cast<__hip_bfloat16*>(wb)[idx] =
        __float2bfloat16(a.w1[which][idx & 65535]);
  }
  if (idx < 9 * 65536) {
    // wt[tap][o][c] = kdw[o][c][tap]
    const int tap = idx >> 16;
    const int o = (idx >> 8) & 255;
    const int c = idx & 255;
    reinterpret_cast<__hip_bfloat16*>(wt)[idx] =
        __float2bfloat16(a.kdw[o * 2304 + c * 9 + tap]);
  }
}

// ---------------- fused GEMM ----------------
struct Job {
  const uint16_t* A;   // bf16 activations (x1 padded NHWC, or x2 NHWC)
  const uint16_t* W;   // bf16 weights [O][C] (mode 3: 9 stacked per-tap matrices)
  const float* bias;   // f32
  float* out;          // f32 NHWC
  int mtiles;
  int mode;  // 0: x1 1x1 (padded addr), 1: x2 1x1, 2: x2 1x1 + 2x upsample, 3: conv3x3 s2
};
struct JobArgs {
  Job j[8];
};

// block = 256 threads (4 waves, 2x2), tile 128x128, BK=32, mfma 16x16x32 bf16
__global__ __launch_bounds__(256, 2) void fused_gemm(JobArgs args) {
  const Job jb = args.j[blockIdx.z];
  if ((int)blockIdx.x >= jb.mtiles) return;
  const int mtile = blockIdx.x;
  const int ntile = blockIdx.y;
  const int mode = jb.mode;

  __shared__ __align__(16) uint16_t lA[128 * 32];
  __shared__ __align__(16) uint16_t lB[128 * 32];

  const int tid = threadIdx.x;
  const int lane = tid & 63;
  const int wave = tid >> 6;
  const int wr = wave & 1;
  const int wc = wave >> 1;

  // staging: 512 16B chunks per tile; chunk cid -> row=cid>>2, kchunk=cid&3
  const int cid0 = wave * 128 + lane;
  const int cid1 = cid0 + 64;
  const int rA0 = cid0 >> 2, kc0 = cid0 & 3;
  const int rA1 = cid1 >> 2, kc1 = cid1 & 3;

  long abase0, abase1;
  {
    const int m0 = mtile * 128 + rA0;
    const int m1 = mtile * 128 + rA1;
    if (mode == 0) {
      // x1 padded: [2][130][130][256], m = b*16384 + h*128 + w
      abase0 = ((long)((m0 >> 14) * 130 + ((m0 >> 7) & 127) + 1) * 130 +
                (m0 & 127) + 1) * 256;
      abase1 = ((long)((m1 >> 14) * 130 + ((m1 >> 7) & 127) + 1) * 130 +
                (m1 & 127) + 1) * 256;
    } else if (mode == 3) {
      // conv3x3 s2: m = b*4096 + oh*64 + ow ; padded base at (2*oh, 2*ow)
      abase0 = ((long)((m0 >> 12) * 130 + 2 * ((m0 >> 6) & 63)) * 130 +
                2 * (m0 & 63)) * 256;
      abase1 = ((long)((m1 >> 12) * 130 + 2 * ((m1 >> 6) & 63)) * 130 +
                2 * (m1 & 63)) * 256;
    } else {
      abase0 = (long)m0 * 256;
      abase1 = (long)m1 * 256;
    }
  }
  const uint16_t* pa0 = jb.A + abase0 + kc0 * 8;
  const uint16_t* pa1 = jb.A + abase1 + kc1 * 8;
  const uint16_t* pb0 = jb.W + (long)(ntile * 128 + rA0) * 256 + kc0 * 8;
  const uint16_t* pb1 = jb.W + (long)(ntile * 128 + rA1) * 256 + kc1 * 8;

  // wave-uniform LDS dests (1024B per wave-call)
  uint16_t* dA0 = lA + wave * 1024;
  uint16_t* dA1 = dA0 + 512;
  uint16_t* dB0 = lB + wave * 1024;
  uint16_t* dB1 = dB0 + 512;

  const int q = lane >> 4;
  const int l15 = lane & 15;
  const uint16_t* ra[4];
  const uint16_t* rb[4];
#pragma unroll
  for (int i = 0; i < 4; i++) {
    ra[i] = lA + (wr * 64 + i * 16 + l15) * 32 + q * 8;
    rb[i] = lB + (wc * 64 + i * 16 + l15) * 32 + q * 8;
  }

  f32x4 acc[4][4] = {};

  auto step = [&](int ks, bool conv) {
    long aoff, woff;
    if (conv) {
      const int tap = ks >> 3;
      const int k0 = (ks & 7) * 32;
      const int kh = tap / 3;
      const int kw = tap - kh * 3;
      aoff = (long)(kh * 130 + kw) * 256 + k0;
      woff = (long)tap * 65536 + k0;
    } else {
      aoff = woff = (long)ks * 32;
    }
    __syncthreads();  // previous iter's ds_reads done before overwrite
    cp16(dA0, pa0 + aoff);
    cp16(dA1, pa1 + aoff);
    cp16(dB0, pb0 + woff);
    cp16(dB1, pb1 + woff);
    __syncthreads();  // drains vmcnt before barrier (compiler-inserted)
    bf16x8 af[4], bfr[4];
#pragma unroll
    for (int i = 0; i < 4; i++) af[i] = *(const bf16x8*)ra[i];
#pragma unroll
    for (int i = 0; i < 4; i++) bfr[i] = *(const bf16x8*)rb[i];
#pragma unroll
    for (int i = 0; i < 4; i++)
#pragma unroll
      for (int j = 0; j < 4; j++)
        acc[i][j] = __builtin_amdgcn_mfma_f32_16x16x32_bf16(af[i], bfr[j],
                                                            acc[i][j], 0, 0, 0);
  };

  if (mode == 3) {
    for (int ks = 0; ks < 72; ks++) step(ks, true);
  } else {
#pragma unroll
    for (int ks = 0; ks < 8; ks++) step(ks, false);
  }

  // epilogue: C/D layout col=lane&15, row=quad*4+reg (verified m89/m91)
  const int nbase = ntile * 128 + wc * 64 + l15;
  const int mbase = mtile * 128 + wr * 64 + q * 4;
#pragma unroll
  for (int j = 0; j < 4; j++) {
    const int n = nbase + j * 16;
    const float bv = jb.bias[n];
#pragma unroll
    for (int i = 0; i < 4; i++) {
      const int m0 = mbase + i * 16;
      const f32x4 v = acc[i][j];
      if (mode == 2) {
#pragma unroll
        for (int r = 0; r < 4; r++) {
          const int m = m0 + r;  // b*4096 + h2*64 + w2
          const int b = m >> 12;
          const int h2 = (m >> 6) & 63;
          const int w2 = m & 63;
          const float val = v[r] + bv;
          float* o = jb.out + ((long)(b * 128 + 2 * h2) * 128 + 2 * w2) * 256 + n;
          o[0] = val;
          o[256] = val;
          o[32768] = val;
          o[32768 + 256] = val;
        }
      } else {
#pragma unroll
        for (int r = 0; r < 4; r++) {
          jb.out[(long)(m0 + r) * 256 + n] = v[r] + bv;
        }
      }
    }
  }
}

extern "C" void kernel_launch(void* const* d_in, const int* in_sizes, int n_in,
                              void* d_out, int out_size, void* d_ws,
                              size_t ws_size, hipStream_t stream) {
  (void)in_sizes; (void)n_in; (void)out_size; (void)ws_size;
  const float* x1 = (const float*)d_in[0];
  const float* x2 = (const float*)d_in[1];
  float* out = (float*)d_out;

  // ws layout (bf16 elements)
  uint16_t* x1p = (uint16_t*)d_ws;        // [2][130][130][256] = 8,652,800
  uint16_t* x2b = x1p + 8652800;          // [2][64][64][256]   = 2,097,152
  uint16_t* wb = x2b + 2097152;           // 7 x [256][256]     =   458,752
  uint16_t* wt = wb + 7 * 65536;          // 9 x [256][256]     =   589,824

  hipMemsetAsync(x1p, 0, 8652800 * sizeof(uint16_t), stream);  // zero pad ring
  nchw2nhwc_bf16<<<dim3(2, 4, 256), 256, 0, stream>>>(x1, x1p, 128, 128, 1);
  nchw2nhwc_bf16<<<dim3(1, 4, 128), 256, 0, stream>>>(x2, x2b, 64, 64, 0);

  WArgs wa;
  wa.w1[0] = (const float*)d_in[2];   // q1_w
  wa.w1[1] = (const float*)d_in[4];   // q2_w
  wa.w1[2] = (const float*)d_in[6];   // ks1_w
  wa.w1[3] = (const float*)d_in[8];   // ks2_w
  wa.w1[4] = (const float*)d_in[10];  // kup_w
  wa.w1[5] = (const float*)d_in[12];  // v1_w
  wa.w1[6] = (const float*)d_in[14];  // v2_w
  wa.kdw = (const float*)d_in[16];    // kdown_w
  convert_weights<<<2304, 256, 0, stream>>>(wa, wb, wt);

  // d_out float offsets (tuple order):
  // q1:0  q2:8388608  k_up:10485760  k_self1:18874368  k_self2:27262976
  // k_down:29360128  v1:31457280  v2:39845888
  JobArgs ja;
  ja.j[0] = {x1p, wt,             (const float*)d_in[17], out + 29360128L, 64, 3};  // kdown first (longest)
  ja.j[1] = {x1p, wb + 0 * 65536, (const float*)d_in[3],  out + 0L,        256, 0}; // q1
  ja.j[2] = {x1p, wb + 2 * 65536, (const float*)d_in[7],  out + 18874368L, 256, 0}; // ks1
  ja.j[3] = {x1p, wb + 5 * 65536, (const float*)d_in[13], out + 31457280L, 256, 0}; // v1
  ja.j[4] = {x2b, wb + 4 * 65536, (const float*)d_in[11], out + 10485760L, 64, 2};  // kup (upsample)
  ja.j[5] = {x2b, wb + 1 * 65536, (const float*)d_in[5],  out + 8388608L,  64, 1};  // q2
  ja.j[6] = {x2b, wb + 3 * 65536, (const float*)d_in[9],  out + 27262976L, 64, 1};  // ks2
  ja.j[7] = {x2b, wb + 6 * 65536, (const float*)d_in[15], out + 39845888L, 64, 1};  // v2
  fused_gemm<<<dim3(256, 2, 8), 256, 0, stream>>>(ja);
}